// Round 2
// baseline (508.054 us; speedup 1.0000x reference)
//
#include <hip/hip_runtime.h>
#include <cstdint>

#define Bn 64
#define Ln 512
#define Hn 768
#define Tn 16
#define Cn 8     // chunks over L
#define Sn 64    // chunk length
#define LOG16 2.7725887222397812f

// ---------------- K1: logits = hs @ W^T + bias, then per-row normalize ----------------
// em'[b,l,t] = logit - max_t(logit) - log(16).  The per-(b,l) shift cancels exactly in
// llh = numer - denom (mask is all-ones; both sides absorb Sum_l sh[b,l]) and is
// argmax-invariant for Viterbi; keeps linear-space CRF chunk products stable.
__global__ __launch_bounds__(64) void k_logits(
    const float* __restrict__ hs, const float* __restrict__ W,
    const float* __restrict__ bias, float* __restrict__ em) {
  int row = blockIdx.x * 64 + threadIdx.x;   // one thread per (b,l) row; W reads are wave-uniform -> s_load
  const float* h = hs + (size_t)row * Hn;
  float acc[Tn];
#pragma unroll
  for (int t = 0; t < Tn; ++t) acc[t] = bias[t];
#pragma unroll 8
  for (int e = 0; e < Hn; e += 4) {
    float4 hv = *(const float4*)(h + e);
#pragma unroll
    for (int t = 0; t < Tn; ++t) {
      const float* w = W + t * Hn + e;
      acc[t] = fmaf(hv.x, w[0], acc[t]);
      acc[t] = fmaf(hv.y, w[1], acc[t]);
      acc[t] = fmaf(hv.z, w[2], acc[t]);
      acc[t] = fmaf(hv.w, w[3], acc[t]);
    }
  }
  float mx = acc[0];
#pragma unroll
  for (int t = 1; t < Tn; ++t) mx = fmaxf(mx, acc[t]);
  float sh = mx + LOG16;
  float4* o4 = (float4*)(em + (size_t)row * Tn);   // 64B/lane contiguous -> coalesced
  o4[0] = make_float4(acc[0]-sh, acc[1]-sh, acc[2]-sh, acc[3]-sh);
  o4[1] = make_float4(acc[4]-sh, acc[5]-sh, acc[6]-sh, acc[7]-sh);
  o4[2] = make_float4(acc[8]-sh, acc[9]-sh, acc[10]-sh, acc[11]-sh);
  o4[3] = make_float4(acc[12]-sh, acc[13]-sh, acc[14]-sh, acc[15]-sh);
}

// ---------------- K2: CRF numerator per batch (uses shifted em; shift cancels vs denom) --
__global__ __launch_bounds__(256) void k_numer(
    const float* __restrict__ em, const int* __restrict__ labels,
    const int* __restrict__ mask, const float* __restrict__ start,
    const float* __restrict__ endt, const float* __restrict__ trans,
    float* __restrict__ numer) {
  int b = blockIdx.x, tid = threadIdx.x;
  float s = 0.f; int msum = 0;
  for (int l = tid; l < Ln; l += 256) {
    int y = labels[b*Ln + l];
    int m = mask[b*Ln + l];
    msum += m;
    if (l == 0) {
      s += start[y] + em[((size_t)b*Ln)*Tn + y];
    } else if (m) {
      int yp = labels[b*Ln + l - 1];
      s += trans[yp*Tn + y] + em[((size_t)b*Ln + l)*Tn + y];
    }
  }
  for (int off = 32; off; off >>= 1) {
    s += __shfl_down(s, off);
    msum += __shfl_down(msum, off);
  }
  __shared__ float sw[4]; __shared__ int mw[4];
  int wid = tid >> 6, ln = tid & 63;
  if (ln == 0) { sw[wid] = s; mw[wid] = msum; }
  __syncthreads();
  if (tid == 0) {
    float st = sw[0]+sw[1]+sw[2]+sw[3];
    int mt = mw[0]+mw[1]+mw[2]+mw[3];
    int last = labels[b*Ln + mt - 1];
    numer[b] = st + endt[last];
  }
}

// ---------------- K3: denominator chunk matrices (linear-space matrix product chain) ----
// Block per (b,chunk).  thread (i,t') holds P[i][t'].  P <- (P . exp(trans)) * exp(em'[l]).
// Per-row renorm every 16 steps with tracked log-scale.  Output: Q_c = log(P) + logs.
__global__ __launch_bounds__(256) void k_denom_chunk(
    const float* __restrict__ em, const int* __restrict__ mask,
    const float* __restrict__ trans, float* __restrict__ qmat) {
  int bc = blockIdx.x, b = bc >> 3, c = bc & 7;
  int tid = threadIdx.x, i = tid >> 4, tp = tid & 15;
  int l0 = c * Sn;
  __shared__ float ems[Sn * Tn];
  __shared__ int msk[Sn];
  const float* src = em + ((size_t)b*Ln + l0)*Tn;
  for (int k = tid; k < Sn*Tn; k += 256) ems[k] = src[k];
  if (tid < Sn) msk[tid] = mask[b*Ln + l0 + tid];
  float etr[Tn];
#pragma unroll
  for (int t = 0; t < Tn; ++t) etr[t] = __expf(trans[t*Tn + tp]);
  __syncthreads();
  float p = (tp == i) ? 1.f : 0.f;   // identity row i
  float logs = 0.f;
  int lstart = (c == 0) ? 1 : l0;
  for (int l = lstart; l < l0 + Sn; ++l) {
    float cs = __expf(ems[(l - l0)*Tn + tp]);
    float dot = 0.f;
#pragma unroll
    for (int t = 0; t < Tn; ++t) dot = fmaf(__shfl(p, t, 16), etr[t], dot);
    float pn = dot * cs;
    p = msk[l - l0] ? pn : p;
    if ((l & 15) == 15) {            // per-row renorm; last trigger is the final step
      float m = p;
      m = fmaxf(m, __shfl_xor(m, 1));
      m = fmaxf(m, __shfl_xor(m, 2));
      m = fmaxf(m, __shfl_xor(m, 4));
      m = fmaxf(m, __shfl_xor(m, 8));
      p /= m;
      logs += __logf(m);
    }
  }
  qmat[(((size_t)b*Cn + c)*Tn + i)*Tn + tp] = __logf(p) + logs;
}

// ---------------- K5: Viterbi chunk matrices + per-chunk argmax history -----------------
__global__ __launch_bounds__(256) void k_vit_chunk(
    const float* __restrict__ em, const float* __restrict__ trans,
    float* __restrict__ qv, uint8_t* __restrict__ hist) {
  int bc = blockIdx.x, b = bc >> 3, c = bc & 7;
  int tid = threadIdx.x, i = tid >> 4, tp = tid & 15;
  int l0 = c * Sn;
  __shared__ float ems[Sn * Tn];
  __shared__ uint8_t hl[Tn * Sn * Tn];    // [i][l'][t'] 16KB
  const float* src = em + ((size_t)b*Ln + l0)*Tn;
  for (int k = tid; k < Sn*Tn; k += 256) ems[k] = src[k];
  float tcol[Tn];
#pragma unroll
  for (int t = 0; t < Tn; ++t) tcol[t] = trans[t*Tn + tp];
  __syncthreads();
  float v = (tp == i) ? 0.f : -1e30f;     // max-plus identity row i
  int lstart = (c == 0) ? 1 : l0;
  for (int l = lstart; l < l0 + Sn; ++l) {
    float best = -3.0e38f; int arg = 0;
#pragma unroll
    for (int t = 0; t < Tn; ++t) {        // strict > keeps FIRST max (jnp.argmax semantics)
      float cand = __shfl(v, t, 16) + tcol[t];
      bool g = cand > best;
      arg = g ? t : arg;
      best = g ? cand : best;
    }
    v = best + ems[(l - l0)*Tn + tp];
    hl[(i*Sn + (l - l0))*Tn + tp] = (uint8_t)arg;
  }
  qv[(((size_t)b*Cn + c)*Tn + i)*Tn + tp] = v;
  __syncthreads();
  const uint4* s4 = (const uint4*)hl;     // coalesced 16KB dump
  uint4* d4 = (uint4*)(hist + (size_t)bc * (Tn*Sn*Tn));
  for (int k = tid; k < (Tn*Sn*Tn)/16; k += 256) d4[k] = s4[k];
}

// ---------------- K4: fold denominator chunks (log-space), compute loss -----------------
__global__ __launch_bounds__(1024) void k_loss(
    const float* __restrict__ qmat, const float* __restrict__ em,
    const float* __restrict__ start, const float* __restrict__ endt,
    const float* __restrict__ numer, float* __restrict__ out) {
  int tid = threadIdx.x, b = tid >> 4, k = tid & 15;   // 64 batches x 16 lanes
  float p = start[k] + em[((size_t)b*Ln)*Tn + k];
  for (int c = 0; c < Cn; ++c) {
    float vals[Tn]; float mx = -3.0e38f;
#pragma unroll
    for (int i = 0; i < Tn; ++i) {
      float cand = __shfl(p, i, 16) + qmat[(((size_t)b*Cn + c)*Tn + i)*Tn + k];
      vals[i] = cand;
      mx = fmaxf(mx, cand);
    }
    float sm = 0.f;
#pragma unroll
    for (int i = 0; i < Tn; ++i) sm += __expf(vals[i] - mx);
    p = mx + __logf(sm);
  }
  float x = p + endt[k];
  float mx = x;
  mx = fmaxf(mx, __shfl_xor(mx, 1));
  mx = fmaxf(mx, __shfl_xor(mx, 2));
  mx = fmaxf(mx, __shfl_xor(mx, 4));
  mx = fmaxf(mx, __shfl_xor(mx, 8));
  float e = __expf(x - mx);
  e += __shfl_xor(e, 1);
  e += __shfl_xor(e, 2);
  e += __shfl_xor(e, 4);
  e += __shfl_xor(e, 8);
  float denom = mx + __logf(e);
  __shared__ float red[Bn];
  if (k == 0) red[b] = numer[b] - denom;
  __syncthreads();
  if (tid < 64) {
    float vv = red[tid];
    for (int off = 32; off; off >>= 1) vv += __shfl_down(vv, off);
    if (tid == 0) out[0] = -vv * (1.0f / Bn);
  }
}

// ---------------- K6: Viterbi fold + parallel per-chunk backtrack -----------------------
__global__ __launch_bounds__(512) void k_vit_bt(
    const float* __restrict__ qv, const float* __restrict__ em,
    const float* __restrict__ start, const float* __restrict__ endt,
    const uint8_t* __restrict__ hist, float* __restrict__ tags) {
  int b = blockIdx.x, tid = threadIdx.x;
  __shared__ int Bs[Cn][Tn];
  __shared__ int bnd[Cn + 1];
  if (tid < Tn) {
    int k = tid;
    float p = start[k] + em[((size_t)b*Ln)*Tn + k];
    for (int c = 0; c < Cn; ++c) {
      float best = -3.0e38f; int arg = 0;
#pragma unroll
      for (int i = 0; i < Tn; ++i) {
        float cand = __shfl(p, i, 16) + qv[(((size_t)b*Cn + c)*Tn + i)*Tn + k];
        bool g = cand > best;
        arg = g ? i : arg;
        best = g ? cand : best;
      }
      Bs[c][k] = arg;
      p = best;
    }
    float x = p + endt[k]; int idx = k;   // first-max argmax over k
#pragma unroll
    for (int d = 1; d < 16; d <<= 1) {
      float xo = __shfl_xor(x, d);
      int io = __shfl_xor(idx, d);
      bool take = (xo > x) || (xo == x && io < idx);
      x = take ? xo : x;
      idx = take ? io : idx;
    }
    if (k == 0) bnd[Cn] = idx;
  }
  __syncthreads();
  if (tid == 0) {                         // boundary states via fold backpointers
    int t = bnd[Cn];
    for (int c = Cn - 1; c >= 0; --c) { t = Bs[c][t]; bnd[c] = t; }
  }
  __syncthreads();
  int w = tid >> 6, lane = tid & 63;      // wave w backtracks chunk w
  int istar = bnd[w];
  int cur = bnd[w + 1];
  int l0 = w * Sn;
  const uint4* hp = (const uint4*)(hist + ((size_t)(b*Cn + w)*Tn + istar)*(Sn*Tn));
  uint4 hh = hp[lane];                    // lane l' holds hist bytes for step l0+l'
  float mytag = (lane == 63) ? (float)cur : 0.f;
  for (int l = l0 + 63; l >= l0 + 1; --l) {
    int sl = l - l0;
    unsigned w0 = __shfl((int)hh.x, sl);
    unsigned w1 = __shfl((int)hh.y, sl);
    unsigned w2 = __shfl((int)hh.z, sl);
    unsigned w3 = __shfl((int)hh.w, sl);
    unsigned word = (cur < 8) ? ((cur < 4) ? w0 : w1) : ((cur < 12) ? w2 : w3);
    cur = (int)((word >> ((cur & 3) * 8)) & 0xff);
    if (lane == sl - 1) mytag = (float)cur;
  }
  tags[(size_t)b*Ln + l0 + lane] = mytag; // coalesced
}

extern "C" void kernel_launch(void* const* d_in, const int* in_sizes, int n_in,
                              void* d_out, int out_size, void* d_ws, size_t ws_size,
                              hipStream_t stream) {
  const float* hs     = (const float*)d_in[0];
  const int*   mask   = (const int*)d_in[1];
  const int*   labels = (const int*)d_in[2];
  const float* W      = (const float*)d_in[3];
  const float* bias   = (const float*)d_in[4];
  const float* start  = (const float*)d_in[5];
  const float* endt   = (const float*)d_in[6];
  const float* trans  = (const float*)d_in[7];
  float* out = (float*)d_out;

  // Workspace layout (ROUND-1 BUG FIX: qmat/qv are 512 KB each = B*C*T*T*4,
  // previous layout overlapped qv/numer/hist on top of qmat):
  //   em    @ 0        : 64*512*16*4 = 2,097,152 B
  //   qmat  @ 2 MB     : 64*8*16*16*4 =  524,288 B
  //   qv    @ 2.5 MB   :                 524,288 B
  //   numer @ 3 MB     :                     256 B (padded to 4 KB)
  //   hist  @ 3 MB+4KB : 64*8*16*64*16 = 8,388,608 B   -> total ~11.1 MB
  char* ws = (char*)d_ws;
  float*   em    = (float*)(ws);
  float*   qmat  = (float*)(ws + (size_t)(1u<<21));
  float*   qv    = (float*)(ws + (size_t)(1u<<21) + 524288);
  float*   numer = (float*)(ws + (size_t)(1u<<21) + 1048576);
  uint8_t* hist  = (uint8_t*)(ws + (size_t)(1u<<21) + 1048576 + 4096);

  hipLaunchKernelGGL(k_logits,      dim3(512), dim3(64),   0, stream, hs, W, bias, em);
  hipLaunchKernelGGL(k_numer,       dim3(64),  dim3(256),  0, stream, em, labels, mask, start, endt, trans, numer);
  hipLaunchKernelGGL(k_denom_chunk, dim3(512), dim3(256),  0, stream, em, mask, trans, qmat);
  hipLaunchKernelGGL(k_vit_chunk,   dim3(512), dim3(256),  0, stream, em, trans, qv, hist);
  hipLaunchKernelGGL(k_loss,        dim3(1),   dim3(1024), 0, stream, qmat, em, start, endt, numer, out);
  hipLaunchKernelGGL(k_vit_bt,      dim3(64),  dim3(512),  0, stream, qv, em, start, endt, hist, out + 1);
}

// Round 3
// 286.902 us; speedup vs baseline: 1.7708x; 1.7708x over previous
//
#include <hip/hip_runtime.h>
#include <cstdint>

#define Bn 64
#define Ln 512
#define Hn 768
#define Tn 16
#define Cn 8     // chunks over L
#define Sn 64    // chunk length
#define Kn 8     // K-split for GEMM
#define Kc 96    // K-chunk per GEMM block (768/8)
#define LOG16 2.7725887222397812f

// ---------------- K1a: partial GEMM, split-K, LDS-staged A ----------------
// Grid: 512 row-tiles x 8 K-slices (bx&511 = row tile, bx>>9 = K slice).
// Block = 1 wave = 64 threads = 64 rows.  A tile staged coalesced into LDS
// (row stride 100 floats: 16B-aligned, spreads banks).  W reads are
// block-uniform -> compiler emits s_load (verified: SGPR=112, VALUBusy 7.7%
// in round-2).  Output partial[row][s][t]: one aligned 64B line per thread.
__global__ __launch_bounds__(64) void k_gemm_part(
    const float* __restrict__ hs, const float* __restrict__ W,
    float* __restrict__ partial) {
  int bx = blockIdx.x;
  int rt = bx & 511, s = bx >> 9;
  int tid = threadIdx.x;
  int r0 = rt * 64, kb = s * Kc;
  __shared__ float alds[64 * 100];   // 25,600 B -> 6 blocks/CU
#pragma unroll
  for (int it = 0; it < 24; ++it) {  // 1536 float4 = 64 rows x 24
    unsigned flat = it * 64u + tid;
    unsigned r = flat / 24u, j = flat % 24u;   // 384B contiguous runs per row
    float4 v = *(const float4*)(hs + (size_t)(r0 + r) * Hn + kb + j * 4);
    *(float4*)&alds[r * 100 + j * 4] = v;
  }
  __syncthreads();
  float acc[Tn] = {0.f};
  for (int k4 = 0; k4 < 24; ++k4) {
    float4 a = *(const float4*)&alds[tid * 100 + k4 * 4];
#pragma unroll
    for (int t = 0; t < Tn; ++t) {
      const float* w = W + t * Hn + kb + k4 * 4;   // uniform -> s_load
      acc[t] = fmaf(a.x, w[0], fmaf(a.y, w[1], fmaf(a.z, w[2], fmaf(a.w, w[3], acc[t]))));
    }
  }
  float* dst = partial + (size_t)(r0 + tid) * (Kn * Tn) + s * Tn;  // 64B line
  *(float4*)(dst + 0)  = make_float4(acc[0],  acc[1],  acc[2],  acc[3]);
  *(float4*)(dst + 4)  = make_float4(acc[4],  acc[5],  acc[6],  acc[7]);
  *(float4*)(dst + 8)  = make_float4(acc[8],  acc[9],  acc[10], acc[11]);
  *(float4*)(dst + 12) = make_float4(acc[12], acc[13], acc[14], acc[15]);
}

// ---------------- K1b: reduce split-K partials, bias, per-row shift ----------------
// lane = (row quad, t): reads coalesced 64B segments, writes em coalesced.
__global__ __launch_bounds__(256) void k_reduce(
    const float* __restrict__ partial, const float* __restrict__ bias,
    float* __restrict__ em) {
  int tid = threadIdx.x;
  int row = blockIdx.x * 16 + (tid >> 4), t = tid & 15;
  const float* p = partial + (size_t)row * (Kn * Tn) + t;
  float sum = bias[t];
#pragma unroll
  for (int s = 0; s < Kn; ++s) sum += p[s * Tn];
  float mx = sum;
  mx = fmaxf(mx, __shfl_xor(mx, 1));
  mx = fmaxf(mx, __shfl_xor(mx, 2));
  mx = fmaxf(mx, __shfl_xor(mx, 4));
  mx = fmaxf(mx, __shfl_xor(mx, 8));
  em[(size_t)row * Tn + t] = sum - (mx + LOG16);
}

// ---------------- K2: CRF numerator per batch (uses shifted em; shift cancels vs denom) --
__global__ __launch_bounds__(256) void k_numer(
    const float* __restrict__ em, const int* __restrict__ labels,
    const int* __restrict__ mask, const float* __restrict__ start,
    const float* __restrict__ endt, const float* __restrict__ trans,
    float* __restrict__ numer) {
  int b = blockIdx.x, tid = threadIdx.x;
  float s = 0.f; int msum = 0;
  for (int l = tid; l < Ln; l += 256) {
    int y = labels[b*Ln + l];
    int m = mask[b*Ln + l];
    msum += m;
    if (l == 0) {
      s += start[y] + em[((size_t)b*Ln)*Tn + y];
    } else if (m) {
      int yp = labels[b*Ln + l - 1];
      s += trans[yp*Tn + y] + em[((size_t)b*Ln + l)*Tn + y];
    }
  }
  for (int off = 32; off; off >>= 1) {
    s += __shfl_down(s, off);
    msum += __shfl_down(msum, off);
  }
  __shared__ float sw[4]; __shared__ int mw[4];
  int wid = tid >> 6, ln = tid & 63;
  if (ln == 0) { sw[wid] = s; mw[wid] = msum; }
  __syncthreads();
  if (tid == 0) {
    float st = sw[0]+sw[1]+sw[2]+sw[3];
    int mt = mw[0]+mw[1]+mw[2]+mw[3];
    int last = labels[b*Ln + mt - 1];
    numer[b] = st + endt[last];
  }
}

// ---------------- K3: denominator chunk matrices (linear-space matrix product chain) ----
__global__ __launch_bounds__(256) void k_denom_chunk(
    const float* __restrict__ em, const int* __restrict__ mask,
    const float* __restrict__ trans, float* __restrict__ qmat) {
  int bc = blockIdx.x, b = bc >> 3, c = bc & 7;
  int tid = threadIdx.x, i = tid >> 4, tp = tid & 15;
  int l0 = c * Sn;
  __shared__ float ems[Sn * Tn];
  __shared__ int msk[Sn];
  const float* src = em + ((size_t)b*Ln + l0)*Tn;
  for (int k = tid; k < Sn*Tn; k += 256) ems[k] = src[k];
  if (tid < Sn) msk[tid] = mask[b*Ln + l0 + tid];
  float etr[Tn];
#pragma unroll
  for (int t = 0; t < Tn; ++t) etr[t] = __expf(trans[t*Tn + tp]);
  __syncthreads();
  float p = (tp == i) ? 1.f : 0.f;   // identity row i
  float logs = 0.f;
  int lstart = (c == 0) ? 1 : l0;
  for (int l = lstart; l < l0 + Sn; ++l) {
    float cs = __expf(ems[(l - l0)*Tn + tp]);
    float dot = 0.f;
#pragma unroll
    for (int t = 0; t < Tn; ++t) dot = fmaf(__shfl(p, t, 16), etr[t], dot);
    float pn = dot * cs;
    p = msk[l - l0] ? pn : p;
    if ((l & 15) == 15) {            // per-row renorm; last trigger is the final step
      float m = p;
      m = fmaxf(m, __shfl_xor(m, 1));
      m = fmaxf(m, __shfl_xor(m, 2));
      m = fmaxf(m, __shfl_xor(m, 4));
      m = fmaxf(m, __shfl_xor(m, 8));
      p /= m;
      logs += __logf(m);
    }
  }
  qmat[(((size_t)b*Cn + c)*Tn + i)*Tn + tp] = __logf(p) + logs;
}

// ---------------- K5: Viterbi chunk matrices + per-chunk argmax history -----------------
__global__ __launch_bounds__(256) void k_vit_chunk(
    const float* __restrict__ em, const float* __restrict__ trans,
    float* __restrict__ qv, uint8_t* __restrict__ hist) {
  int bc = blockIdx.x, b = bc >> 3, c = bc & 7;
  int tid = threadIdx.x, i = tid >> 4, tp = tid & 15;
  int l0 = c * Sn;
  __shared__ float ems[Sn * Tn];
  __shared__ uint8_t hl[Tn * Sn * Tn];    // [i][l'][t'] 16KB
  const float* src = em + ((size_t)b*Ln + l0)*Tn;
  for (int k = tid; k < Sn*Tn; k += 256) ems[k] = src[k];
  float tcol[Tn];
#pragma unroll
  for (int t = 0; t < Tn; ++t) tcol[t] = trans[t*Tn + tp];
  __syncthreads();
  float v = (tp == i) ? 0.f : -1e30f;     // max-plus identity row i
  int lstart = (c == 0) ? 1 : l0;
  for (int l = lstart; l < l0 + Sn; ++l) {
    float best = -3.0e38f; int arg = 0;
#pragma unroll
    for (int t = 0; t < Tn; ++t) {        // strict > keeps FIRST max (jnp.argmax semantics)
      float cand = __shfl(v, t, 16) + tcol[t];
      bool g = cand > best;
      arg = g ? t : arg;
      best = g ? cand : best;
    }
    v = best + ems[(l - l0)*Tn + tp];
    hl[(i*Sn + (l - l0))*Tn + tp] = (uint8_t)arg;
  }
  qv[(((size_t)b*Cn + c)*Tn + i)*Tn + tp] = v;
  __syncthreads();
  const uint4* s4 = (const uint4*)hl;     // coalesced 16KB dump
  uint4* d4 = (uint4*)(hist + (size_t)bc * (Tn*Sn*Tn));
  for (int k = tid; k < (Tn*Sn*Tn)/16; k += 256) d4[k] = s4[k];
}

// ---------------- K4: fold denominator chunks (log-space), compute loss -----------------
__global__ __launch_bounds__(1024) void k_loss(
    const float* __restrict__ qmat, const float* __restrict__ em,
    const float* __restrict__ start, const float* __restrict__ endt,
    const float* __restrict__ numer, float* __restrict__ out) {
  int tid = threadIdx.x, b = tid >> 4, k = tid & 15;   // 64 batches x 16 lanes
  float p = start[k] + em[((size_t)b*Ln)*Tn + k];
  for (int c = 0; c < Cn; ++c) {
    float vals[Tn]; float mx = -3.0e38f;
#pragma unroll
    for (int i = 0; i < Tn; ++i) {
      float cand = __shfl(p, i, 16) + qmat[(((size_t)b*Cn + c)*Tn + i)*Tn + k];
      vals[i] = cand;
      mx = fmaxf(mx, cand);
    }
    float sm = 0.f;
#pragma unroll
    for (int i = 0; i < Tn; ++i) sm += __expf(vals[i] - mx);
    p = mx + __logf(sm);
  }
  float x = p + endt[k];
  float mx = x;
  mx = fmaxf(mx, __shfl_xor(mx, 1));
  mx = fmaxf(mx, __shfl_xor(mx, 2));
  mx = fmaxf(mx, __shfl_xor(mx, 4));
  mx = fmaxf(mx, __shfl_xor(mx, 8));
  float e = __expf(x - mx);
  e += __shfl_xor(e, 1);
  e += __shfl_xor(e, 2);
  e += __shfl_xor(e, 4);
  e += __shfl_xor(e, 8);
  float denom = mx + __logf(e);
  __shared__ float red[Bn];
  if (k == 0) red[b] = numer[b] - denom;
  __syncthreads();
  if (tid < 64) {
    float vv = red[tid];
    for (int off = 32; off; off >>= 1) vv += __shfl_down(vv, off);
    if (tid == 0) out[0] = -vv * (1.0f / Bn);
  }
}

// ---------------- K6: Viterbi fold + parallel per-chunk backtrack -----------------------
__global__ __launch_bounds__(512) void k_vit_bt(
    const float* __restrict__ qv, const float* __restrict__ em,
    const float* __restrict__ start, const float* __restrict__ endt,
    const uint8_t* __restrict__ hist, float* __restrict__ tags) {
  int b = blockIdx.x, tid = threadIdx.x;
  __shared__ int Bs[Cn][Tn];
  __shared__ int bnd[Cn + 1];
  if (tid < Tn) {
    int k = tid;
    float p = start[k] + em[((size_t)b*Ln)*Tn + k];
    for (int c = 0; c < Cn; ++c) {
      float best = -3.0e38f; int arg = 0;
#pragma unroll
      for (int i = 0; i < Tn; ++i) {
        float cand = __shfl(p, i, 16) + qv[(((size_t)b*Cn + c)*Tn + i)*Tn + k];
        bool g = cand > best;
        arg = g ? i : arg;
        best = g ? cand : best;
      }
      Bs[c][k] = arg;
      p = best;
    }
    float x = p + endt[k]; int idx = k;   // first-max argmax over k
#pragma unroll
    for (int d = 1; d < 16; d <<= 1) {
      float xo = __shfl_xor(x, d);
      int io = __shfl_xor(idx, d);
      bool take = (xo > x) || (xo == x && io < idx);
      x = take ? xo : x;
      idx = take ? io : idx;
    }
    if (k == 0) bnd[Cn] = idx;
  }
  __syncthreads();
  if (tid == 0) {                         // boundary states via fold backpointers
    int t = bnd[Cn];
    for (int c = Cn - 1; c >= 0; --c) { t = Bs[c][t]; bnd[c] = t; }
  }
  __syncthreads();
  int w = tid >> 6, lane = tid & 63;      // wave w backtracks chunk w
  int istar = bnd[w];
  int cur = bnd[w + 1];
  int l0 = w * Sn;
  const uint4* hp = (const uint4*)(hist + ((size_t)(b*Cn + w)*Tn + istar)*(Sn*Tn));
  uint4 hh = hp[lane];                    // lane l' holds hist bytes for step l0+l'
  float mytag = (lane == 63) ? (float)cur : 0.f;
  for (int l = l0 + 63; l >= l0 + 1; --l) {
    int sl = l - l0;
    unsigned w0 = __shfl((int)hh.x, sl);
    unsigned w1 = __shfl((int)hh.y, sl);
    unsigned w2 = __shfl((int)hh.z, sl);
    unsigned w3 = __shfl((int)hh.w, sl);
    unsigned word = (cur < 8) ? ((cur < 4) ? w0 : w1) : ((cur < 12) ? w2 : w3);
    cur = (int)((word >> ((cur & 3) * 8)) & 0xff);
    if (lane == sl - 1) mytag = (float)cur;
  }
  tags[(size_t)b*Ln + l0 + lane] = mytag; // coalesced
}

extern "C" void kernel_launch(void* const* d_in, const int* in_sizes, int n_in,
                              void* d_out, int out_size, void* d_ws, size_t ws_size,
                              hipStream_t stream) {
  const float* hs     = (const float*)d_in[0];
  const int*   mask   = (const int*)d_in[1];
  const int*   labels = (const int*)d_in[2];
  const float* W      = (const float*)d_in[3];
  const float* bias   = (const float*)d_in[4];
  const float* start  = (const float*)d_in[5];
  const float* endt   = (const float*)d_in[6];
  const float* trans  = (const float*)d_in[7];
  float* out = (float*)d_out;

  // Workspace layout (~19.9 MB):
  //   em      @ 0        : 64*512*16*4 = 2,097,152 B
  //   qmat    @ 2 MB     : 64*8*16*16*4 =  524,288 B
  //   qv      @ 2.5 MB   :                 524,288 B
  //   numer   @ 3 MB     :                     256 B (padded to 4 KB)
  //   partial @ 3 MB+4KB : 32768*8*16*4 = 16,777,216 B  (dies at k_reduce)
  //   hist    @ 3 MB+4KB : 8,388,608 B  ALIASES partial (born at k_vit_chunk)
  char* ws = (char*)d_ws;
  float*   em      = (float*)(ws);
  float*   qmat    = (float*)(ws + (size_t)(1u<<21));
  float*   qv      = (float*)(ws + (size_t)(1u<<21) + 524288);
  float*   numer   = (float*)(ws + (size_t)(1u<<21) + 1048576);
  float*   partial = (float*)(ws + (size_t)(1u<<21) + 1048576 + 4096);
  uint8_t* hist    = (uint8_t*)(ws + (size_t)(1u<<21) + 1048576 + 4096);

  hipLaunchKernelGGL(k_gemm_part,   dim3(4096), dim3(64),  0, stream, hs, W, partial);
  hipLaunchKernelGGL(k_reduce,      dim3(2048), dim3(256), 0, stream, partial, bias, em);
  hipLaunchKernelGGL(k_numer,       dim3(64),   dim3(256), 0, stream, em, labels, mask, start, endt, trans, numer);
  hipLaunchKernelGGL(k_denom_chunk, dim3(512),  dim3(256), 0, stream, em, mask, trans, qmat);
  hipLaunchKernelGGL(k_vit_chunk,   dim3(512),  dim3(256), 0, stream, em, trans, qv, hist);
  hipLaunchKernelGGL(k_loss,        dim3(1),    dim3(1024),0, stream, qmat, em, start, endt, numer, out);
  hipLaunchKernelGGL(k_vit_bt,      dim3(64),   dim3(512), 0, stream, qv, em, start, endt, hist, out + 1);
}